// Round 7
// baseline (142.345 us; speedup 1.0000x reference)
//
#include <hip/hip_runtime.h>

#define N_NODES 100000
#define NEDGE   1600000
#define D       32

#define BSHIFT   7
#define BNODES   128                                  // nodes per bucket
#define NBUCKET  ((N_NODES + BNODES - 1) / BNODES)    // 782
#define NB_PAD   784
#define EPB      8192                                 // edges per block in bin pass
#define EPT      (EPB / 256)                          // 32 edges per thread
#define CBLK     ((NEDGE + EPB - 1) / EPB)            // 196
#define CAP      3072                                 // max edges/bucket for LDS path (mean 2046, sd~45)

// ---------- Kernel A: per-bucket edge histogram ----------
__global__ void bucket_hist_kernel(const int* __restrict__ dst, int* __restrict__ bucket_cnt) {
    __shared__ int h[NB_PAD];
    for (int i = threadIdx.x; i < NB_PAD; i += blockDim.x) h[i] = 0;
    __syncthreads();
    for (int e = blockIdx.x * blockDim.x + threadIdx.x; e < NEDGE; e += gridDim.x * blockDim.x)
        atomicAdd(&h[dst[e] >> BSHIFT], 1);
    __syncthreads();
    for (int i = threadIdx.x; i < NB_PAD; i += blockDim.x)
        if (h[i]) atomicAdd(&bucket_cnt[i], h[i]);
}

// ---------- Kernel B: exclusive scan of 784 bucket counts (1 block, 1024 thr) ----------
__global__ void bucket_scan_kernel(const int* __restrict__ bucket_cnt,
                                   int* __restrict__ bucket_off, int* __restrict__ bucket_cur) {
    __shared__ int s[1024];
    int tid = threadIdx.x;
    int v = (tid < NB_PAD) ? bucket_cnt[tid] : 0;
    s[tid] = v;
    __syncthreads();
    for (int o = 1; o < 1024; o <<= 1) {
        int t = (tid >= o) ? s[tid - o] : 0;
        __syncthreads();
        s[tid] += t;
        __syncthreads();
    }
    if (tid < NB_PAD) {
        int excl = s[tid] - v;
        bucket_off[tid] = excl;
        bucket_cur[tid] = excl;
    }
}

// ---------- Kernel C: bin edges, coalesced write-out via in-LDS bucket sort ----------
// packed: x = src | (dst_local << 17)   (src < 2^17, dst_local < 128), y = w bits
__global__ __launch_bounds__(256) void bin_edges_kernel(
        const int* __restrict__ src, const int* __restrict__ dst,
        const float* __restrict__ w,
        int* __restrict__ bucket_cur, int2* __restrict__ binned) {
    __shared__ int2 sorted[EPB];                 // 64 KB
    __shared__ unsigned short bucketOf[EPB];     // 16 KB
    __shared__ int cnt[NB_PAD];                  // hist, then local cursor
    __shared__ int ndoff[NB_PAD];                // local exclusive scan
    __shared__ int delta[NB_PAD];                // global_base - local_base
    __shared__ int partial[256];

    const int tid = threadIdx.x;
    const int e0  = blockIdx.x * EPB;
    const int total = min(EPB, NEDGE - e0);

    for (int i = tid; i < NB_PAD; i += 256) cnt[i] = 0;
    __syncthreads();

    // Phase 1: histogram; keep dst in statically-indexed registers
    int myd[EPT];
    #pragma unroll
    for (int it = 0; it < EPT; ++it) {
        int e = e0 + it * 256 + tid;
        myd[it] = (e < NEDGE) ? dst[e] : -1;
        if (myd[it] >= 0) atomicAdd(&cnt[myd[it] >> BSHIFT], 1);
    }
    __syncthreads();

    // Phase 2: local scan over 784 buckets (4 per thread) + global run claim
    {
        int b0 = tid * 4;
        int c0 = 0, c1 = 0, c2 = 0, c3 = 0, s = 0;
        if (b0 < NB_PAD) { c0 = cnt[b0]; c1 = cnt[b0+1]; c2 = cnt[b0+2]; c3 = cnt[b0+3];
                           s = c0 + c1 + c2 + c3; }
        partial[tid] = s;
        __syncthreads();
        int v = s;
        for (int o = 1; o < 256; o <<= 1) {
            int t2 = (tid >= o) ? partial[tid - o] : 0;
            __syncthreads();
            partial[tid] += t2;
            __syncthreads();
        }
        int run = partial[tid] - v;
        if (b0 < NB_PAD) {
            int cs[4] = {c0, c1, c2, c3};
            #pragma unroll
            for (int j = 0; j < 4; ++j) {
                int b = b0 + j;
                ndoff[b] = run;
                if (cs[j] > 0) delta[b] = atomicAdd(&bucket_cur[b], cs[j]) - run;
                cnt[b] = 0;   // reset as local cursor (only owner read it)
                run += cs[j];
            }
        }
    }
    __syncthreads();

    // Phase 3: scatter into LDS (coalesced src/w loads, random LDS writes)
    #pragma unroll
    for (int it = 0; it < EPT; ++it) {
        int d = myd[it];
        if (d >= 0) {
            int e = e0 + it * 256 + tid;
            int b = d >> BSHIFT;
            int r = atomicAdd(&cnt[b], 1);
            int loc = ndoff[b] + r;
            sorted[loc]   = make_int2(src[e] | ((d & (BNODES - 1)) << 17),
                                      __float_as_int(w[e]));
            bucketOf[loc] = (unsigned short)b;
        }
    }
    __syncthreads();

    // Phase 4: coalesced write-out (consecutive slots -> consecutive gaddr per run)
    for (int i = tid; i < total; i += 256) {
        int2 v = sorted[i];
        int  b = bucketOf[i];
        binned[delta[b] + i] = v;
    }
}

// ---------- Kernel D: per-bucket CSR slice build (coalesced out) ----------
__global__ void build_csr_kernel(const int* __restrict__ bucket_off, const int* __restrict__ bucket_cnt,
                                 const int2* __restrict__ binned,
                                 int2* __restrict__ csr, int* __restrict__ off, int* __restrict__ deg) {
    __shared__ int2 stage[CAP];
    __shared__ int2 sorted[CAP];
    __shared__ int ndcnt[BNODES];
    __shared__ int ndoff[BNODES];
    __shared__ int s[BNODES];

    int b = blockIdx.x;
    int tid = threadIdx.x;
    int start = bucket_off[b];
    int cnt_b = bucket_cnt[b];
    bool fast = (cnt_b <= CAP);

    if (tid < BNODES) ndcnt[tid] = 0;
    if (fast)
        for (int i = tid; i < cnt_b; i += blockDim.x) stage[i] = binned[start + i];
    __syncthreads();

    if (fast) {
        for (int i = tid; i < cnt_b; i += blockDim.x)
            atomicAdd(&ndcnt[(stage[i].x >> 17) & (BNODES - 1)], 1);
    } else {
        for (int i = tid; i < cnt_b; i += blockDim.x)
            atomicAdd(&ndcnt[(binned[start + i].x >> 17) & (BNODES - 1)], 1);
    }
    __syncthreads();

    int v = (tid < BNODES) ? ndcnt[tid] : 0;
    if (tid < BNODES) s[tid] = v;
    __syncthreads();
    for (int o = 1; o < BNODES; o <<= 1) {
        int t = (tid < BNODES && tid >= o) ? s[tid - o] : 0;
        __syncthreads();
        if (tid < BNODES) s[tid] += t;
        __syncthreads();
    }
    if (tid < BNODES) {
        ndoff[tid] = s[tid] - v;
        int node = b * BNODES + tid;
        if (node < N_NODES) {
            off[node] = start + ndoff[tid];
            deg[node] = v;
        }
        ndcnt[tid] = 0;   // reuse as cursor
    }
    __syncthreads();

    if (fast) {
        for (int i = tid; i < cnt_b; i += blockDim.x) {
            int2 p = stage[i];
            int dl = (p.x >> 17) & (BNODES - 1);
            int r = atomicAdd(&ndcnt[dl], 1);
            sorted[ndoff[dl] + r] = make_int2(p.x & 0x1FFFF, p.y);
        }
        __syncthreads();
        for (int i = tid; i < cnt_b; i += blockDim.x) csr[start + i] = sorted[i];
    } else {
        for (int i = tid; i < cnt_b; i += blockDim.x) {
            int2 p = binned[start + i];
            int dl = (p.x >> 17) & (BNODES - 1);
            int r = atomicAdd(&ndcnt[dl], 1);
            csr[start + ndoff[dl] + r] = make_int2(p.x & 0x1FFFF, p.y);
        }
    }
}

// ---------- gather SpMM (no atomics, register acc, 2-way unrolled) ----------
__global__ void spmm_gather_kernel(const int* __restrict__ off, const int* __restrict__ deg,
                                   const int2* __restrict__ csr_sw,
                                   const float* __restrict__ x, float* __restrict__ out) {
    int gid = blockIdx.x * blockDim.x + threadIdx.x;
    if (gid >= N_NODES * 8) return;
    int node = gid >> 3;
    int c    = gid & 7;
    int start = off[node];
    int len   = deg[node];
    float4 acc = {0.f, 0.f, 0.f, 0.f};
    int k = 0;
    for (; k + 2 <= len; k += 2) {
        int2 sw0 = csr_sw[start + k];
        int2 sw1 = csr_sw[start + k + 1];
        const float4 xv0 = *reinterpret_cast<const float4*>(&x[(long)sw0.x * D + c * 4]);
        const float4 xv1 = *reinterpret_cast<const float4*>(&x[(long)sw1.x * D + c * 4]);
        float w0 = __int_as_float(sw0.y);
        float w1 = __int_as_float(sw1.y);
        acc.x += w0 * xv0.x; acc.y += w0 * xv0.y; acc.z += w0 * xv0.z; acc.w += w0 * xv0.w;
        acc.x += w1 * xv1.x; acc.y += w1 * xv1.y; acc.z += w1 * xv1.z; acc.w += w1 * xv1.w;
    }
    if (k < len) {
        int2 sw = csr_sw[start + k];
        const float4 xv = *reinterpret_cast<const float4*>(&x[(long)sw.x * D + c * 4]);
        float wt = __int_as_float(sw.y);
        acc.x += wt * xv.x; acc.y += wt * xv.y; acc.z += wt * xv.z; acc.w += wt * xv.w;
    }
    *reinterpret_cast<float4*>(&out[(long)node * D + c * 4]) = acc;
}

// ---------- fallback (atomic scatter) if ws too small ----------
__global__ void spmm_scatter_kernel(const int* __restrict__ src, const int* __restrict__ dst,
                                    const float* __restrict__ w, const float* __restrict__ x,
                                    float* __restrict__ out) {
    long gid = (long)blockIdx.x * blockDim.x + threadIdx.x;
    if (gid >= (long)NEDGE * 8) return;
    int e = (int)(gid >> 3);
    int c = (int)(gid & 7);
    int s = src[e], d = dst[e];
    float wt = w[e];
    const float4 xv = *reinterpret_cast<const float4*>(&x[(long)s * D + c * 4]);
    float* o = &out[(long)d * D + c * 4];
    atomicAdd(o + 0, wt * xv.x);
    atomicAdd(o + 1, wt * xv.y);
    atomicAdd(o + 2, wt * xv.z);
    atomicAdd(o + 3, wt * xv.w);
}

extern "C" void kernel_launch(void* const* d_in, const int* in_sizes, int n_in,
                              void* d_out, int out_size, void* d_ws, size_t ws_size,
                              hipStream_t stream) {
    const float* x    = (const float*)d_in[0];
    const int*   esrc = (const int*)d_in[1];
    const int*   edst = (const int*)d_in[2];
    const float* ew   = (const float*)d_in[3];
    float* out = (float*)d_out;

    char* ws = (char*)d_ws;
    const size_t y_bytes = (size_t)N_NODES * D * sizeof(float);   // 12.8 MB (== binned bytes)
    const size_t n_ints  = (size_t)N_NODES * sizeof(int);         // 400 KB
    const size_t b_ints  = (size_t)NB_PAD * sizeof(int);
    const size_t e_sw    = (size_t)NEDGE * sizeof(int2);          // 12.8 MB

    size_t o = 0;
    float* y          = (float*)(ws + o); o += y_bytes;           // aliases `binned`
    int2*  csr        = (int2*) (ws + o); o += e_sw;
    int*   off        = (int*)  (ws + o); o += n_ints;
    int*   deg        = (int*)  (ws + o); o += n_ints;
    int*   bucket_cnt = (int*)  (ws + o); o += b_ints;
    int*   bucket_off = (int*)  (ws + o); o += b_ints;
    int*   bucket_cur = (int*)  (ws + o); o += b_ints;
    int2*  binned     = (int2*)y;   // reuse: binned dead once csr built, y live after

    if (ws_size < o) {
        hipMemsetAsync(y, 0, y_bytes, stream);
        hipMemsetAsync(out, 0, y_bytes, stream);
        const long total = (long)NEDGE * 8;
        const int blocks = (int)((total + 255) / 256);
        spmm_scatter_kernel<<<blocks, 256, 0, stream>>>(esrc, edst, ew, x, y);
        spmm_scatter_kernel<<<blocks, 256, 0, stream>>>(esrc, edst, ew, y, out);
        return;
    }

    hipMemsetAsync(bucket_cnt, 0, b_ints, stream);

    bucket_hist_kernel<<<256, 256, 0, stream>>>(edst, bucket_cnt);
    bucket_scan_kernel<<<1, 1024, 0, stream>>>(bucket_cnt, bucket_off, bucket_cur);
    bin_edges_kernel<<<CBLK, 256, 0, stream>>>(esrc, edst, ew, bucket_cur, binned);
    build_csr_kernel<<<NBUCKET, 256, 0, stream>>>(bucket_off, bucket_cnt, binned, csr, off, deg);

    const int gblocks = (N_NODES * 8 + 255) / 256;
    spmm_gather_kernel<<<gblocks, 256, 0, stream>>>(off, deg, csr, x, y);
    spmm_gather_kernel<<<gblocks, 256, 0, stream>>>(off, deg, csr, y, out);
}

// Round 8
// 126.312 us; speedup vs baseline: 1.1269x; 1.1269x over previous
//
#include <hip/hip_runtime.h>

#define N_NODES 100000
#define NEDGE   1600000
#define D       32

#define BSHIFT   8
#define BNODES   256                                  // nodes per bucket
#define NBUCKET  ((N_NODES + BNODES - 1) / BNODES)    // 391
#define NB_PAD   392
#define EPB      4096                                 // edges per block in bin pass
#define EPT      (EPB / 256)                          // 16 edges per thread
#define CBLK     ((NEDGE + EPB - 1) / EPB)            // 391
#define CAP      4608                                 // max edges/bucket for LDS path (mean 4092, sd~64)

// ---------- Kernel A: per-bucket edge histogram ----------
__global__ void bucket_hist_kernel(const int* __restrict__ dst, int* __restrict__ bucket_cnt) {
    __shared__ int h[NB_PAD];
    for (int i = threadIdx.x; i < NB_PAD; i += blockDim.x) h[i] = 0;
    __syncthreads();
    for (int e = blockIdx.x * blockDim.x + threadIdx.x; e < NEDGE; e += gridDim.x * blockDim.x)
        atomicAdd(&h[dst[e] >> BSHIFT], 1);
    __syncthreads();
    for (int i = threadIdx.x; i < NB_PAD; i += blockDim.x)
        if (h[i]) atomicAdd(&bucket_cnt[i], h[i]);
}

// ---------- Kernel B: exclusive scan of 392 bucket counts (1 block, 512 thr) ----------
__global__ void bucket_scan_kernel(const int* __restrict__ bucket_cnt,
                                   int* __restrict__ bucket_off, int* __restrict__ bucket_cur) {
    __shared__ int s[512];
    int tid = threadIdx.x;
    int v = (tid < NB_PAD) ? bucket_cnt[tid] : 0;
    s[tid] = v;
    __syncthreads();
    for (int o = 1; o < 512; o <<= 1) {
        int t = (tid >= o) ? s[tid - o] : 0;
        __syncthreads();
        s[tid] += t;
        __syncthreads();
    }
    if (tid < NB_PAD) {
        int excl = s[tid] - v;
        bucket_off[tid] = excl;
        bucket_cur[tid] = excl;
    }
}

// ---------- Kernel C: bin edges, coalesced write-out via in-LDS bucket sort ----------
// packed: x = src | (dst_local << 17)   (src < 2^17, dst_local < 256), y = w bits
__global__ __launch_bounds__(256) void bin_edges_kernel(
        const int* __restrict__ src, const int* __restrict__ dst,
        const float* __restrict__ w,
        int* __restrict__ bucket_cur, int2* __restrict__ binned) {
    __shared__ int2 sorted[EPB];                 // 32 KB
    __shared__ unsigned short bucketOf[EPB];     //  8 KB
    __shared__ int cnt[NB_PAD];                  // hist, then local cursor
    __shared__ int ndoff[NB_PAD];                // local exclusive scan
    __shared__ int delta[NB_PAD];                // global_base - local_base
    __shared__ int partial[256];

    const int tid = threadIdx.x;
    const int e0  = blockIdx.x * EPB;
    const int total = min(EPB, NEDGE - e0);

    for (int i = tid; i < NB_PAD; i += 256) cnt[i] = 0;
    __syncthreads();

    // Phase 1: histogram; keep dst in statically-indexed registers
    int myd[EPT];
    #pragma unroll
    for (int it = 0; it < EPT; ++it) {
        int e = e0 + it * 256 + tid;
        myd[it] = (e < NEDGE) ? dst[e] : -1;
        if (myd[it] >= 0) atomicAdd(&cnt[myd[it] >> BSHIFT], 1);
    }
    __syncthreads();

    // Phase 2: local scan over 392 buckets (2 per thread) + global run claim
    {
        int b0 = tid * 2;
        int c0 = 0, c1 = 0, s = 0;
        if (b0 < NB_PAD) { c0 = cnt[b0]; c1 = cnt[b0 + 1]; s = c0 + c1; }
        partial[tid] = s;
        __syncthreads();
        int v = s;
        for (int o = 1; o < 256; o <<= 1) {
            int t2 = (tid >= o) ? partial[tid - o] : 0;
            __syncthreads();
            partial[tid] += t2;
            __syncthreads();
        }
        int run = partial[tid] - v;
        if (b0 < NB_PAD) {
            ndoff[b0] = run;
            if (c0 > 0) delta[b0] = atomicAdd(&bucket_cur[b0], c0) - run;
            cnt[b0] = 0;
            run += c0;
            ndoff[b0 + 1] = run;
            if (c1 > 0) delta[b0 + 1] = atomicAdd(&bucket_cur[b0 + 1], c1) - run;
            cnt[b0 + 1] = 0;
            run += c1;
        }
    }
    __syncthreads();

    // Phase 3: scatter into LDS (coalesced src/w loads, random LDS writes)
    #pragma unroll
    for (int it = 0; it < EPT; ++it) {
        int d = myd[it];
        if (d >= 0) {
            int e = e0 + it * 256 + tid;
            int b = d >> BSHIFT;
            int r = atomicAdd(&cnt[b], 1);
            int loc = ndoff[b] + r;
            sorted[loc]   = make_int2(src[e] | ((d & (BNODES - 1)) << 17),
                                      __float_as_int(w[e]));
            bucketOf[loc] = (unsigned short)b;
        }
    }
    __syncthreads();

    // Phase 4: coalesced write-out (consecutive slots -> consecutive gaddr per run)
    for (int i = tid; i < total; i += 256) {
        int2 v = sorted[i];
        int  b = bucketOf[i];
        binned[delta[b] + i] = v;
    }
}

// ---------- Kernel D: per-bucket CSR slice node-sort, IN PLACE ----------
// Block b owns binned[start, start+cnt) exclusively; fast path fully stages the
// slice in LDS before rewriting it, so in-place is safe. Oversized buckets
// (>CAP, ~8 sigma, never expected) stage through the y buffer (dead here).
__global__ __launch_bounds__(256) void build_csr_kernel(
        const int* __restrict__ bucket_off, const int* __restrict__ bucket_cnt,
        int2* __restrict__ binned, int* __restrict__ offv, int* __restrict__ deg,
        int2* __restrict__ ovf) {
    __shared__ int2 stage[CAP];
    __shared__ int2 sorted[CAP];
    __shared__ int ndcnt[BNODES];
    __shared__ int ndoff[BNODES];

    int b = blockIdx.x;
    int tid = threadIdx.x;
    int start = bucket_off[b];
    int cnt_b = bucket_cnt[b];
    bool fast = (cnt_b <= CAP);

    ndcnt[tid] = 0;
    if (fast) {
        for (int i = tid; i < cnt_b; i += 256) stage[i] = binned[start + i];
    } else {
        for (int i = tid; i < cnt_b; i += 256) ovf[i] = binned[start + i];
    }
    __syncthreads();

    // node histogram
    if (fast) {
        for (int i = tid; i < cnt_b; i += 256)
            atomicAdd(&ndcnt[(stage[i].x >> 17) & (BNODES - 1)], 1);
    } else {
        for (int i = tid; i < cnt_b; i += 256)
            atomicAdd(&ndcnt[(ovf[i].x >> 17) & (BNODES - 1)], 1);
    }
    __syncthreads();

    // exclusive scan of 256 node counts (blockDim == BNODES == 256)
    int v = ndcnt[tid];
    ndoff[tid] = v;
    __syncthreads();
    for (int o = 1; o < BNODES; o <<= 1) {
        int t = (tid >= o) ? ndoff[tid - o] : 0;
        __syncthreads();
        ndoff[tid] += t;
        __syncthreads();
    }
    {
        int incl = ndoff[tid];
        __syncthreads();
        ndoff[tid] = incl - v;       // exclusive
        int node = b * BNODES + tid;
        if (node < N_NODES) {
            offv[node] = start + incl - v;
            deg[node]  = v;
        }
        ndcnt[tid] = 0;              // reuse as cursor
    }
    __syncthreads();

    if (fast) {
        for (int i = tid; i < cnt_b; i += 256) {
            int2 p = stage[i];
            int dl = (p.x >> 17) & (BNODES - 1);
            int r = atomicAdd(&ndcnt[dl], 1);
            sorted[ndoff[dl] + r] = make_int2(p.x & 0x1FFFF, p.y);
        }
        __syncthreads();
        for (int i = tid; i < cnt_b; i += 256) binned[start + i] = sorted[i];
    } else {
        for (int i = tid; i < cnt_b; i += 256) {
            int2 p = ovf[i];
            int dl = (p.x >> 17) & (BNODES - 1);
            int r = atomicAdd(&ndcnt[dl], 1);
            binned[start + ndoff[dl] + r] = make_int2(p.x & 0x1FFFF, p.y);
        }
    }
}

// ---------- gather SpMM (no atomics, register acc, 4-way unrolled) ----------
// 8 threads per node; each owns a float4 slice of the 32-wide feature row.
__global__ void spmm_gather_kernel(const int* __restrict__ off, const int* __restrict__ deg,
                                   const int2* __restrict__ csr_sw,
                                   const float* __restrict__ x, float* __restrict__ out) {
    int gid = blockIdx.x * blockDim.x + threadIdx.x;
    if (gid >= N_NODES * 8) return;
    int node = gid >> 3;
    int c    = gid & 7;
    int start = off[node];
    int len   = deg[node];
    float4 acc = {0.f, 0.f, 0.f, 0.f};
    int k = 0;
    for (; k + 4 <= len; k += 4) {
        int2 sw0 = csr_sw[start + k];
        int2 sw1 = csr_sw[start + k + 1];
        int2 sw2 = csr_sw[start + k + 2];
        int2 sw3 = csr_sw[start + k + 3];
        const float4 xv0 = *reinterpret_cast<const float4*>(&x[(long)sw0.x * D + c * 4]);
        const float4 xv1 = *reinterpret_cast<const float4*>(&x[(long)sw1.x * D + c * 4]);
        const float4 xv2 = *reinterpret_cast<const float4*>(&x[(long)sw2.x * D + c * 4]);
        const float4 xv3 = *reinterpret_cast<const float4*>(&x[(long)sw3.x * D + c * 4]);
        float w0 = __int_as_float(sw0.y), w1 = __int_as_float(sw1.y);
        float w2 = __int_as_float(sw2.y), w3 = __int_as_float(sw3.y);
        acc.x += w0 * xv0.x; acc.y += w0 * xv0.y; acc.z += w0 * xv0.z; acc.w += w0 * xv0.w;
        acc.x += w1 * xv1.x; acc.y += w1 * xv1.y; acc.z += w1 * xv1.z; acc.w += w1 * xv1.w;
        acc.x += w2 * xv2.x; acc.y += w2 * xv2.y; acc.z += w2 * xv2.z; acc.w += w2 * xv2.w;
        acc.x += w3 * xv3.x; acc.y += w3 * xv3.y; acc.z += w3 * xv3.z; acc.w += w3 * xv3.w;
    }
    for (; k < len; ++k) {
        int2 sw = csr_sw[start + k];
        const float4 xv = *reinterpret_cast<const float4*>(&x[(long)sw.x * D + c * 4]);
        float wt = __int_as_float(sw.y);
        acc.x += wt * xv.x; acc.y += wt * xv.y; acc.z += wt * xv.z; acc.w += wt * xv.w;
    }
    *reinterpret_cast<float4*>(&out[(long)node * D + c * 4]) = acc;
}

// ---------- fallback (atomic scatter) if ws too small ----------
__global__ void spmm_scatter_kernel(const int* __restrict__ src, const int* __restrict__ dst,
                                    const float* __restrict__ w, const float* __restrict__ x,
                                    float* __restrict__ out) {
    long gid = (long)blockIdx.x * blockDim.x + threadIdx.x;
    if (gid >= (long)NEDGE * 8) return;
    int e = (int)(gid >> 3);
    int c = (int)(gid & 7);
    int s = src[e], d = dst[e];
    float wt = w[e];
    const float4 xv = *reinterpret_cast<const float4*>(&x[(long)s * D + c * 4]);
    float* o = &out[(long)d * D + c * 4];
    atomicAdd(o + 0, wt * xv.x);
    atomicAdd(o + 1, wt * xv.y);
    atomicAdd(o + 2, wt * xv.z);
    atomicAdd(o + 3, wt * xv.w);
}

extern "C" void kernel_launch(void* const* d_in, const int* in_sizes, int n_in,
                              void* d_out, int out_size, void* d_ws, size_t ws_size,
                              hipStream_t stream) {
    const float* x    = (const float*)d_in[0];
    const int*   esrc = (const int*)d_in[1];
    const int*   edst = (const int*)d_in[2];
    const float* ew   = (const float*)d_in[3];
    float* out = (float*)d_out;

    char* ws = (char*)d_ws;
    const size_t y_bytes = (size_t)N_NODES * D * sizeof(float);   // 12.8 MB
    const size_t n_ints  = (size_t)N_NODES * sizeof(int);         // 400 KB
    const size_t b_ints  = (size_t)NB_PAD * sizeof(int);
    const size_t e_sw    = (size_t)NEDGE * sizeof(int2);          // 12.8 MB

    size_t o = 0;
    float* y          = (float*)(ws + o); o += y_bytes;           // also oversize staging
    int2*  binned     = (int2*) (ws + o); o += e_sw;              // CSR built in place
    int*   off        = (int*)  (ws + o); o += n_ints;
    int*   deg        = (int*)  (ws + o); o += n_ints;
    int*   bucket_cnt = (int*)  (ws + o); o += b_ints;
    int*   bucket_off = (int*)  (ws + o); o += b_ints;
    int*   bucket_cur = (int*)  (ws + o); o += b_ints;

    if (ws_size < o) {
        hipMemsetAsync(y, 0, y_bytes, stream);
        hipMemsetAsync(out, 0, y_bytes, stream);
        const long total = (long)NEDGE * 8;
        const int blocks = (int)((total + 255) / 256);
        spmm_scatter_kernel<<<blocks, 256, 0, stream>>>(esrc, edst, ew, x, y);
        spmm_scatter_kernel<<<blocks, 256, 0, stream>>>(esrc, edst, ew, y, out);
        return;
    }

    hipMemsetAsync(bucket_cnt, 0, b_ints, stream);

    bucket_hist_kernel<<<256, 256, 0, stream>>>(edst, bucket_cnt);
    bucket_scan_kernel<<<1, 512, 0, stream>>>(bucket_cnt, bucket_off, bucket_cur);
    bin_edges_kernel<<<CBLK, 256, 0, stream>>>(esrc, edst, ew, bucket_cur, binned);
    build_csr_kernel<<<NBUCKET, 256, 0, stream>>>(bucket_off, bucket_cnt, binned, off, deg,
                                                  (int2*)y);

    const int gblocks = (N_NODES * 8 + 255) / 256;
    spmm_gather_kernel<<<gblocks, 256, 0, stream>>>(off, deg, binned, x, y);
    spmm_gather_kernel<<<gblocks, 256, 0, stream>>>(off, deg, binned, y, out);
}

// Round 9
// 112.057 us; speedup vs baseline: 1.2703x; 1.1272x over previous
//
#include <hip/hip_runtime.h>

#define N_NODES 100000
#define NEDGE   1600000
#define D       32

#define BSHIFT   8
#define BNODES   256                                  // nodes per bucket
#define NBUCKET  ((N_NODES + BNODES - 1) / BNODES)    // 391
#define NB_PAD   392
#define EPB      4096                                 // edges per block in bin pass
#define EPT      (EPB / 256)                          // 16 edges per thread
#define CBLK     ((NEDGE + EPB - 1) / EPB)            // 391
#define CAP      5120                                 // arena slots per bucket (mean 4096, sd~64 -> 16 sigma)

// ---------- Kernel 0: seed per-bucket cursors to arena starts ----------
__global__ void init_cur_kernel(int* __restrict__ bucket_cur) {
    int i = blockIdx.x * blockDim.x + threadIdx.x;
    if (i < NB_PAD) bucket_cur[i] = i * CAP;
}

// ---------- Kernel C: bin edges into fixed arenas, coalesced write-out ----------
// packed: x = src | (dst_local << 17)   (src < 2^17, dst_local < 256), y = w bits
__global__ __launch_bounds__(256) void bin_edges_kernel(
        const int* __restrict__ src, const int* __restrict__ dst,
        const float* __restrict__ w,
        int* __restrict__ bucket_cur, int2* __restrict__ binned) {
    __shared__ int2 sorted[EPB];                 // 32 KB
    __shared__ unsigned short bucketOf[EPB];     //  8 KB
    __shared__ int cnt[NB_PAD];                  // hist, then local cursor
    __shared__ int ndoff[NB_PAD];                // local exclusive scan
    __shared__ int delta[NB_PAD];                // global_base - local_base
    __shared__ int partial[256];

    const int tid = threadIdx.x;
    const int e0  = blockIdx.x * EPB;
    const int total = min(EPB, NEDGE - e0);

    for (int i = tid; i < NB_PAD; i += 256) cnt[i] = 0;
    __syncthreads();

    // Phase 1: histogram; keep dst in statically-indexed registers
    int myd[EPT];
    #pragma unroll
    for (int it = 0; it < EPT; ++it) {
        int e = e0 + it * 256 + tid;
        myd[it] = (e < NEDGE) ? dst[e] : -1;
        if (myd[it] >= 0) atomicAdd(&cnt[myd[it] >> BSHIFT], 1);
    }
    __syncthreads();

    // Phase 2: local scan over 392 buckets (2 per thread) + global run claim
    {
        int b0 = tid * 2;
        int c0 = 0, c1 = 0, s = 0;
        if (b0 < NB_PAD) { c0 = cnt[b0]; c1 = cnt[b0 + 1]; s = c0 + c1; }
        partial[tid] = s;
        __syncthreads();
        int v = s;
        for (int o = 1; o < 256; o <<= 1) {
            int t2 = (tid >= o) ? partial[tid - o] : 0;
            __syncthreads();
            partial[tid] += t2;
            __syncthreads();
        }
        int run = partial[tid] - v;
        if (b0 < NB_PAD) {
            ndoff[b0] = run;
            if (c0 > 0) delta[b0] = atomicAdd(&bucket_cur[b0], c0) - run;
            cnt[b0] = 0;
            run += c0;
            ndoff[b0 + 1] = run;
            if (c1 > 0) delta[b0 + 1] = atomicAdd(&bucket_cur[b0 + 1], c1) - run;
            cnt[b0 + 1] = 0;
            run += c1;
        }
    }
    __syncthreads();

    // Phase 3: scatter into LDS (coalesced src/w loads, random LDS writes)
    #pragma unroll
    for (int it = 0; it < EPT; ++it) {
        int d = myd[it];
        if (d >= 0) {
            int e = e0 + it * 256 + tid;
            int b = d >> BSHIFT;
            int r = atomicAdd(&cnt[b], 1);
            int loc = ndoff[b] + r;
            sorted[loc]   = make_int2(src[e] | ((d & (BNODES - 1)) << 17),
                                      __float_as_int(w[e]));
            bucketOf[loc] = (unsigned short)b;
        }
    }
    __syncthreads();

    // Phase 4: coalesced write-out (consecutive slots -> consecutive gaddr per run)
    for (int i = tid; i < total; i += 256) {
        int2 v = sorted[i];
        int  b = bucketOf[i];
        binned[delta[b] + i] = v;
    }
}

// ---------- Kernel D: per-bucket CSR slice node-sort, IN PLACE ----------
// Block b owns binned[b*CAP, b*CAP+cnt) exclusively. Slice is read twice from
// global (L2-hot) to keep LDS at ~42KB (3 blocks/CU). LDS scatter then
// coalesced in-place rewrite.
__global__ __launch_bounds__(256) void build_csr_kernel(
        const int* __restrict__ bucket_cur,
        int2* __restrict__ binned, int* __restrict__ offv, int* __restrict__ deg) {
    __shared__ int2 sorted[CAP];                 // 40 KB
    __shared__ int ndcnt[BNODES];
    __shared__ int ndoff[BNODES];

    int b = blockIdx.x;
    int tid = threadIdx.x;
    int start = b * CAP;
    int cnt_b = min(bucket_cur[b] - start, CAP);

    ndcnt[tid] = 0;
    __syncthreads();

    // node histogram (pass 1 over slice)
    for (int i = tid; i < cnt_b; i += 256)
        atomicAdd(&ndcnt[(binned[start + i].x >> 17) & (BNODES - 1)], 1);
    __syncthreads();

    // exclusive scan of 256 node counts (blockDim == BNODES == 256)
    int v = ndcnt[tid];
    ndoff[tid] = v;
    __syncthreads();
    for (int o = 1; o < BNODES; o <<= 1) {
        int t = (tid >= o) ? ndoff[tid - o] : 0;
        __syncthreads();
        ndoff[tid] += t;
        __syncthreads();
    }
    {
        int incl = ndoff[tid];
        __syncthreads();
        ndoff[tid] = incl - v;       // exclusive
        int node = b * BNODES + tid;
        if (node < N_NODES) {
            offv[node] = start + incl - v;
            deg[node]  = v;
        }
        ndcnt[tid] = 0;              // reuse as cursor
    }
    __syncthreads();

    // pass 2: scatter into LDS node-sorted, then coalesced in-place rewrite
    for (int i = tid; i < cnt_b; i += 256) {
        int2 p = binned[start + i];
        int dl = (p.x >> 17) & (BNODES - 1);
        int r = atomicAdd(&ndcnt[dl], 1);
        sorted[ndoff[dl] + r] = make_int2(p.x & 0x1FFFF, p.y);
    }
    __syncthreads();
    for (int i = tid; i < cnt_b; i += 256) binned[start + i] = sorted[i];
}

// ---------- gather SpMM (no atomics, register acc, 4-way unrolled) ----------
// 8 threads per node; each owns a float4 slice of the 32-wide feature row.
__global__ void spmm_gather_kernel(const int* __restrict__ off, const int* __restrict__ deg,
                                   const int2* __restrict__ csr_sw,
                                   const float* __restrict__ x, float* __restrict__ out) {
    int gid = blockIdx.x * blockDim.x + threadIdx.x;
    if (gid >= N_NODES * 8) return;
    int node = gid >> 3;
    int c    = gid & 7;
    int start = off[node];
    int len   = deg[node];
    float4 acc = {0.f, 0.f, 0.f, 0.f};
    int k = 0;
    for (; k + 4 <= len; k += 4) {
        int2 sw0 = csr_sw[start + k];
        int2 sw1 = csr_sw[start + k + 1];
        int2 sw2 = csr_sw[start + k + 2];
        int2 sw3 = csr_sw[start + k + 3];
        const float4 xv0 = *reinterpret_cast<const float4*>(&x[(long)sw0.x * D + c * 4]);
        const float4 xv1 = *reinterpret_cast<const float4*>(&x[(long)sw1.x * D + c * 4]);
        const float4 xv2 = *reinterpret_cast<const float4*>(&x[(long)sw2.x * D + c * 4]);
        const float4 xv3 = *reinterpret_cast<const float4*>(&x[(long)sw3.x * D + c * 4]);
        float w0 = __int_as_float(sw0.y), w1 = __int_as_float(sw1.y);
        float w2 = __int_as_float(sw2.y), w3 = __int_as_float(sw3.y);
        acc.x += w0 * xv0.x; acc.y += w0 * xv0.y; acc.z += w0 * xv0.z; acc.w += w0 * xv0.w;
        acc.x += w1 * xv1.x; acc.y += w1 * xv1.y; acc.z += w1 * xv1.z; acc.w += w1 * xv1.w;
        acc.x += w2 * xv2.x; acc.y += w2 * xv2.y; acc.z += w2 * xv2.z; acc.w += w2 * xv2.w;
        acc.x += w3 * xv3.x; acc.y += w3 * xv3.y; acc.z += w3 * xv3.z; acc.w += w3 * xv3.w;
    }
    for (; k < len; ++k) {
        int2 sw = csr_sw[start + k];
        const float4 xv = *reinterpret_cast<const float4*>(&x[(long)sw.x * D + c * 4]);
        float wt = __int_as_float(sw.y);
        acc.x += wt * xv.x; acc.y += wt * xv.y; acc.z += wt * xv.z; acc.w += wt * xv.w;
    }
    *reinterpret_cast<float4*>(&out[(long)node * D + c * 4]) = acc;
}

// ---------- fallback (atomic scatter) if ws too small ----------
__global__ void spmm_scatter_kernel(const int* __restrict__ src, const int* __restrict__ dst,
                                    const float* __restrict__ w, const float* __restrict__ x,
                                    float* __restrict__ out) {
    long gid = (long)blockIdx.x * blockDim.x + threadIdx.x;
    if (gid >= (long)NEDGE * 8) return;
    int e = (int)(gid >> 3);
    int c = (int)(gid & 7);
    int s = src[e], d = dst[e];
    float wt = w[e];
    const float4 xv = *reinterpret_cast<const float4*>(&x[(long)s * D + c * 4]);
    float* o = &out[(long)d * D + c * 4];
    atomicAdd(o + 0, wt * xv.x);
    atomicAdd(o + 1, wt * xv.y);
    atomicAdd(o + 2, wt * xv.z);
    atomicAdd(o + 3, wt * xv.w);
}

extern "C" void kernel_launch(void* const* d_in, const int* in_sizes, int n_in,
                              void* d_out, int out_size, void* d_ws, size_t ws_size,
                              hipStream_t stream) {
    const float* x    = (const float*)d_in[0];
    const int*   esrc = (const int*)d_in[1];
    const int*   edst = (const int*)d_in[2];
    const float* ew   = (const float*)d_in[3];
    float* out = (float*)d_out;

    char* ws = (char*)d_ws;
    const size_t y_bytes   = (size_t)N_NODES * D * sizeof(float);     // 12.8 MB
    const size_t n_ints    = (size_t)N_NODES * sizeof(int);           // 400 KB
    const size_t b_ints    = (size_t)NB_PAD * sizeof(int);
    const size_t arena_sz  = (size_t)NBUCKET * CAP * sizeof(int2);    // 16.0 MB

    size_t o = 0;
    float* y          = (float*)(ws + o); o += y_bytes;
    int2*  binned     = (int2*) (ws + o); o += arena_sz;              // CSR built in place
    int*   off        = (int*)  (ws + o); o += n_ints;
    int*   deg        = (int*)  (ws + o); o += n_ints;
    int*   bucket_cur = (int*)  (ws + o); o += b_ints;

    if (ws_size < o) {
        hipMemsetAsync(y, 0, y_bytes, stream);
        hipMemsetAsync(out, 0, y_bytes, stream);
        const long total = (long)NEDGE * 8;
        const int blocks = (int)((total + 255) / 256);
        spmm_scatter_kernel<<<blocks, 256, 0, stream>>>(esrc, edst, ew, x, y);
        spmm_scatter_kernel<<<blocks, 256, 0, stream>>>(esrc, edst, ew, y, out);
        return;
    }

    init_cur_kernel<<<2, 256, 0, stream>>>(bucket_cur);
    bin_edges_kernel<<<CBLK, 256, 0, stream>>>(esrc, edst, ew, bucket_cur, binned);
    build_csr_kernel<<<NBUCKET, 256, 0, stream>>>(bucket_cur, binned, off, deg);

    const int gblocks = (N_NODES * 8 + 255) / 256;
    spmm_gather_kernel<<<gblocks, 256, 0, stream>>>(off, deg, binned, x, y);
    spmm_gather_kernel<<<gblocks, 256, 0, stream>>>(off, deg, binned, y, out);
}